// Round 6
// baseline (311.151 us; speedup 1.0000x reference)
//
#include <hip/hip_runtime.h>
#include <hip/hip_bf16.h>
#include <stdint.h>

// Problem constants: B=4, N=4096, D=1024, H=16, M=256, DH=64
#define DATA_SCALE 0.35355339059327373f  // 64^-0.25
#define DN_SCALE   0.0625f               // 0.5 * 64^-0.5

typedef __bf16 bf16x8 __attribute__((ext_vector_type(8)));
typedef float  f32x4  __attribute__((ext_vector_type(4)));

static __device__ __forceinline__ unsigned short f2bf(float f) {
    union { float f; unsigned int u; } v; v.f = f;
    unsigned int r = v.u + 0x7fffu + ((v.u >> 16) & 1u);
    return (unsigned short)(r >> 16);
}

static __device__ __forceinline__ f32x4 mfma16(bf16x8 a, bf16x8 b, f32x4 c) {
    return __builtin_amdgcn_mfma_f32_16x16x32_bf16(a, b, c, 0, 0, 0);
}

static __device__ __forceinline__ void gload16(const void* g, void* lds) {
    __builtin_amdgcn_global_load_lds(
        (const __attribute__((address_space(1))) unsigned int*)g,
        (__attribute__((address_space(3))) unsigned int*)lds, 16, 0, 0);
}

union U8 { unsigned short s[8]; bf16x8 v; };

// ---------------------------------------------------------------- prep ----
__global__ __launch_bounds__(256) void k_prep(const float* __restrict__ W,
                                              const float* __restrict__ proj,
                                              unsigned short* __restrict__ Wb,
                                              unsigned short* __restrict__ projs) {
    int i = blockIdx.x * 256 + threadIdx.x;
    if (i < 1024 * 1024) Wb[i] = f2bf(W[i]);
    if (i < 256 * 64)    projs[i] = f2bf(proj[i] * DATA_SCALE);
}

// ------------------------------------------------------------- k_ctx ------
// R6: n-split S phase. Wave w owns n-rows [16w,16w+16) of each 64-row tile:
// K direct global->A-frags, row-max fully in-wave, exp, kp -> swizzled kpT.
// ctx phase stays m-split (wave w owns m [64w,64w+64)). 2 barriers/tile.
__global__ __launch_bounds__(256) void k_ctx(const float* __restrict__ kg,
                                             const float* __restrict__ vg,
                                             const unsigned short* __restrict__ projs,
                                             float* __restrict__ ctx_part,
                                             float* __restrict__ ksum_part,
                                             int cshift, int ntiles) {
    const int bh = blockIdx.x >> cshift, chunk = blockIdx.x & ((1 << cshift) - 1);
    const int b = bh >> 4, h = bh & 15;
    const int tid = threadIdx.x;
    const int w = tid >> 6, lane = tid & 63, l15 = lane & 15, hh = lane >> 4;

    // kpT[m][n^swz]: row stride 72 u16 = 144B (16B-aligned, 2-way banks)
    __shared__ __align__(16) unsigned short kpT[256][72];
    __shared__ __align__(16) unsigned short VT[64][72];

    f32x4 cacc[4][4];
#pragma unroll
    for (int i = 0; i < 4; ++i)
#pragma unroll
        for (int j = 0; j < 4; ++j) cacc[i][j] = (f32x4){0.f, 0.f, 0.f, 0.f};
    float ksacc[16];
#pragma unroll
    for (int i = 0; i < 16; ++i) ksacc[i] = 0.f;

    const size_t rowoff = (size_t)(b * 4096 + chunk * ntiles * 64) * 1024 + h * 64;

    for (int tt = 0; tt < ntiles; ++tt) {
        __syncthreads();   // A: prev tile's kpT/VT reads complete

        // ---- stage V transposed: VT[dh][n] (thread: row n=lane, 16 dh) ----
        {
            const int n = lane, cs = w * 16;
            const float* src = vg + rowoff + (size_t)(tt*64 + n) * 1024 + cs;
#pragma unroll
            for (int j = 0; j < 16; j += 4) {
                float4 f = *(const float4*)(src + j);
                VT[cs+j+0][n] = f2bf(f.x); VT[cs+j+1][n] = f2bf(f.y);
                VT[cs+j+2][n] = f2bf(f.z); VT[cs+j+3][n] = f2bf(f.w);
            }
        }

        // ---- K direct global -> A-frags (wave rows 16w+l15), s2 in-reg ----
        const float* kb = kg + rowoff + ((size_t)tt*64 + 16*w + l15) * 1024 + hh * 8;
        float4 k0 = *(const float4*)(kb);
        float4 k1 = *(const float4*)(kb + 4);
        float4 k2 = *(const float4*)(kb + 32);
        float4 k3 = *(const float4*)(kb + 36);
        float s2 = k0.x*k0.x + k0.y*k0.y + k0.z*k0.z + k0.w*k0.w
                 + k1.x*k1.x + k1.y*k1.y + k1.z*k1.z + k1.w*k1.w
                 + k2.x*k2.x + k2.y*k2.y + k2.z*k2.z + k2.w*k2.w
                 + k3.x*k3.x + k3.y*k3.y + k3.z*k3.z + k3.w*k3.w;
        s2 += __shfl_xor(s2, 16);
        s2 += __shfl_xor(s2, 32);   // s2 = full |k_row|^2, uniform over hh
        U8 a0, a1;
        a0.s[0]=f2bf(k0.x); a0.s[1]=f2bf(k0.y); a0.s[2]=f2bf(k0.z); a0.s[3]=f2bf(k0.w);
        a0.s[4]=f2bf(k1.x); a0.s[5]=f2bf(k1.y); a0.s[6]=f2bf(k1.z); a0.s[7]=f2bf(k1.w);
        a1.s[0]=f2bf(k2.x); a1.s[1]=f2bf(k2.y); a1.s[2]=f2bf(k2.z); a1.s[3]=f2bf(k2.w);
        a1.s[4]=f2bf(k3.x); a1.s[5]=f2bf(k3.y); a1.s[6]=f2bf(k3.z); a1.s[7]=f2bf(k3.w);

        // ---- S = K @ proj^T : wave's 16 rows x all 256 m ----
        f32x4 sacc[16];
#pragma unroll
        for (int i = 0; i < 16; ++i) sacc[i] = (f32x4){0.f, 0.f, 0.f, 0.f};
#pragma unroll
        for (int ni = 0; ni < 16; ++ni) {
            bf16x8 pb0 = *(const bf16x8*)(projs + (size_t)(16*ni + l15) * 64 + 8*hh);
            sacc[ni] = mfma16(a0.v, pb0, sacc[ni]);
        }
#pragma unroll
        for (int ni = 0; ni < 16; ++ni) {
            bf16x8 pb1 = *(const bf16x8*)(projs + (size_t)(16*ni + l15) * 64 + 32 + 8*hh);
            sacc[ni] = mfma16(a1.v, pb1, sacc[ni]);
        }

        // ---- per-row max over m: in-reg over ni + shfl over l15 ----
        float pm[4];
#pragma unroll
        for (int r = 0; r < 4; ++r) {
            float m01 = fmaxf(sacc[0][r], sacc[1][r]);
#pragma unroll
            for (int ni = 2; ni < 16; ++ni) m01 = fmaxf(m01, sacc[ni][r]);
            pm[r] = m01;
        }
#pragma unroll
        for (int msk = 1; msk <= 8; msk <<= 1)
#pragma unroll
            for (int r = 0; r < 4; ++r)
                pm[r] = fmaxf(pm[r], __shfl_xor(pm[r], msk));
        float offv[4];
#pragma unroll
        for (int r = 0; r < 4; ++r) {
            float s2r = __shfl(s2, (lane & 48) + 4*hh + r);  // lane with l15=4hh+r
            offv[r] = pm[r] + DN_SCALE * s2r;
        }

        // ---- kp = exp(S - off); write swizzled kpT ----
#pragma unroll
        for (int ni = 0; ni < 16; ++ni) {
            float e0 = __expf(sacc[ni][0] - offv[0]);
            float e1 = __expf(sacc[ni][1] - offv[1]);
            float e2 = __expf(sacc[ni][2] - offv[2]);
            float e3 = __expf(sacc[ni][3] - offv[3]);
            ksacc[ni] += e0 + e1 + e2 + e3;
            uint2 pk;
            pk.x = (unsigned int)f2bf(e0) | ((unsigned int)f2bf(e1) << 16);
            pk.y = (unsigned int)f2bf(e2) | ((unsigned int)f2bf(e3) << 16);
            const int colp = (16*w + 4*hh) ^ (8*(ni & 7));   // T2 XOR swizzle
            *(uint2*)&kpT[16*ni + l15][colp] = pk;
        }
        __syncthreads();   // B: kpT + VT ready

        // ---- ctx += kp^T @ V : wave w owns m-slice [64w, 64w+64) ----
#pragma unroll
        for (int ks = 0; ks < 2; ++ks) {
            bf16x8 am[4], bv[4];
#pragma unroll
            for (int mi = 0; mi < 4; ++mi) {
                const int row = 64*w + 16*mi + l15;
                const int s = (4*w + mi) & 7;
                am[mi] = *(const bf16x8*)&kpT[row][8*((4*ks + hh) ^ s)];
            }
#pragma unroll
            for (int ni = 0; ni < 4; ++ni)
                bv[ni] = *(const bf16x8*)&VT[16*ni + l15][ks*32 + 8*hh];
#pragma unroll
            for (int mi = 0; mi < 4; ++mi)
#pragma unroll
                for (int ni = 0; ni < 4; ++ni)
                    cacc[mi][ni] = mfma16(am[mi], bv[ni], cacc[mi][ni]);
        }
    }

    // ---- epilogue: ksum (cross-wave via LDS, reusing VT) + ctx partial ----
#pragma unroll
    for (int ni = 0; ni < 16; ++ni) {
        ksacc[ni] += __shfl_xor(ksacc[ni], 16);
        ksacc[ni] += __shfl_xor(ksacc[ni], 32);
    }
    __syncthreads();                       // VT reads done; safe to reuse
    float* ksW = (float*)&VT[0][0];        // 4 KB <= 9216 B
    if (hh == 0) {
#pragma unroll
        for (int ni = 0; ni < 16; ++ni)
            ksW[w*256 + 16*ni + l15] = ksacc[ni];
    }
    __syncthreads();
    const int pc = blockIdx.x;
    if (tid < 256)
        ksum_part[(size_t)pc * 256 + tid] = ksW[tid] + ksW[256 + tid]
                                          + ksW[512 + tid] + ksW[768 + tid];
    float* cp = ctx_part + (size_t)pc * 256 * 64;
#pragma unroll
    for (int mi = 0; mi < 4; ++mi)
#pragma unroll
        for (int ni = 0; ni < 4; ++ni)
#pragma unroll
            for (int r = 0; r < 4; ++r)
                cp[(64*w + 16*mi + 4*hh + r) * 64 + 16*ni + l15] = cacc[mi][ni][r];
}

// ------------------------------------------------------------ reduce ------
__global__ __launch_bounds__(256) void k_reduce(const float* __restrict__ ctx_part,
                                                const float* __restrict__ ksum_part,
                                                unsigned short* __restrict__ ctxT,
                                                float* __restrict__ ksum, int nchunk) {
    const int bh = blockIdx.x, t = threadIdx.x;
    const float* cp = ctx_part + (size_t)bh * nchunk * 16384;
    f32x4 s[16];
#pragma unroll
    for (int j = 0; j < 16; ++j) s[j] = *(const f32x4*)(cp + t*64 + j*4);
    for (int c = 1; c < nchunk; ++c) {
        const float* cc = cp + (size_t)c * 16384;
#pragma unroll
        for (int j = 0; j < 16; ++j) {
            f32x4 a = *(const f32x4*)(cc + t*64 + j*4);
            s[j] += a;
        }
    }
    unsigned short* ct = ctxT + (size_t)bh * 16384;
#pragma unroll
    for (int j = 0; j < 16; ++j)
#pragma unroll
        for (int e = 0; e < 4; ++e)
            ct[(j*4 + e) * 256 + t] = f2bf(s[j][e]);
    const float* kp_ = ksum_part + (size_t)bh * nchunk * 256;
    float ks = 0.f;
    for (int c = 0; c < nchunk; ++c) ks += kp_[c*256 + t];
    ksum[(size_t)bh * 256 + t] = ks;
}

// ------------------------------------------------------------- k_qout -----
// R6: grid = 64 bh * 64 rowgroups (64 rows); n-split, ZERO barriers.
// Wave w owns rows [16w,16w+16): Q direct->frags, u in wave-private uL,
// den fully in-wave (shfl), rden lane-local.
__global__ __launch_bounds__(256) void k_qout(const float* __restrict__ qg,
                                              const unsigned short* __restrict__ projs,
                                              const unsigned short* __restrict__ ctxT,
                                              const float* __restrict__ ksum,
                                              unsigned short* __restrict__ attn) {
    const int bh = blockIdx.x >> 6, rg = blockIdx.x & 63;
    const int b = bh >> 4, h = bh & 15;
    const int tid = threadIdx.x;
    const int w = tid >> 6, lane = tid & 63, l15 = lane & 15, hh = lane >> 4;

    __shared__ __align__(16) unsigned short uL[4][16][264];

    float ksr[16];
#pragma unroll
    for (int ni = 0; ni < 16; ++ni)
        ksr[ni] = ksum[(size_t)bh * 256 + 16*ni + l15];

    // ---- Q direct global -> A-frags (rows 16w+l15 of this 64-row group) ----
    const float* qb = qg + (size_t)(b*4096 + rg*64 + 16*w + l15) * 1024 + h*64 + hh*8;
    float4 q0 = *(const float4*)(qb);
    float4 q1 = *(const float4*)(qb + 4);
    float4 q2 = *(const float4*)(qb + 32);
    float4 q3 = *(const float4*)(qb + 36);
    U8 a0, a1;
    a0.s[0]=f2bf(q0.x); a0.s[1]=f2bf(q0.y); a0.s[2]=f2bf(q0.z); a0.s[3]=f2bf(q0.w);
    a0.s[4]=f2bf(q1.x); a0.s[5]=f2bf(q1.y); a0.s[6]=f2bf(q1.z); a0.s[7]=f2bf(q1.w);
    a1.s[0]=f2bf(q2.x); a1.s[1]=f2bf(q2.y); a1.s[2]=f2bf(q2.z); a1.s[3]=f2bf(q2.w);
    a1.s[4]=f2bf(q3.x); a1.s[5]=f2bf(q3.y); a1.s[6]=f2bf(q3.z); a1.s[7]=f2bf(q3.w);

    // ---- S_q GEMM: 16 rows x 256 m ----
    f32x4 sacc[16];
#pragma unroll
    for (int i = 0; i < 16; ++i) sacc[i] = (f32x4){0.f, 0.f, 0.f, 0.f};
#pragma unroll
    for (int ni = 0; ni < 16; ++ni) {
        bf16x8 pb0 = *(const bf16x8*)(projs + (size_t)(16*ni + l15) * 64 + 8*hh);
        sacc[ni] = mfma16(a0.v, pb0, sacc[ni]);
    }
#pragma unroll
    for (int ni = 0; ni < 16; ++ni) {
        bf16x8 pb1 = *(const bf16x8*)(projs + (size_t)(16*ni + l15) * 64 + 32 + 8*hh);
        sacc[ni] = mfma16(a1.v, pb1, sacc[ni]);
    }

    // ---- u = exp(S) (q-side offsets cancel); den partials; uL write ----
    float dp[4] = {0.f, 0.f, 0.f, 0.f};
#pragma unroll
    for (int ni = 0; ni < 16; ++ni) {
#pragma unroll
        for (int r = 0; r < 4; ++r) {
            float e = __expf(sacc[ni][r]);
            dp[r] += e * ksr[ni];
            uL[w][4*hh + r][16*ni + l15] = f2bf(e);
        }
    }
    // den: sum over l15 group -> full 256-m sum for row 4hh+r (in-wave)
#pragma unroll
    for (int msk = 1; msk <= 8; msk <<= 1)
#pragma unroll
        for (int r = 0; r < 4; ++r)
            dp[r] += __shfl_xor(dp[r], msk);

    // same-wave LDS write->read: enforce DS ordering
    asm volatile("s_waitcnt lgkmcnt(0)" ::: "memory");
    __builtin_amdgcn_sched_barrier(0);

    // ---- num = u @ ctx : A from wave-private uL, B from ctxT (L2) ----
    const unsigned short* cb = ctxT + (size_t)bh * 16384;
    f32x4 nacc[4];
#pragma unroll
    for (int i = 0; i < 4; ++i) nacc[i] = (f32x4){0.f, 0.f, 0.f, 0.f};
#pragma unroll
    for (int ks = 0; ks < 8; ++ks) {
        bf16x8 a = *(const bf16x8*)&uL[w][l15][ks*32 + 8*hh];
#pragma unroll
        for (int ni = 0; ni < 4; ++ni) {
            bf16x8 bb = *(const bf16x8*)(cb + (size_t)(16*ni + l15) * 256 + ks*32 + 8*hh);
            nacc[ni] = mfma16(a, bb, nacc[ni]);
        }
    }

    // ---- epilogue: attn = num * (1/den), den is lane-local dp[r] ----
#pragma unroll
    for (int r = 0; r < 4; ++r) {
        const float rd = 1.f / dp[r];
        const int grow = rg*64 + 16*w + 4*hh + r;
        unsigned short* dst = attn + (size_t)(b*4096 + grow) * 1024 + h*64;
#pragma unroll
        for (int ni = 0; ni < 4; ++ni)
            dst[16*ni + l15] = f2bf(nacc[ni][r] * rd);
    }
}

// ------------------------------------------------------------ k_linear ----
// out[16384][1024] = attn_bf16 @ Wb^T + bias  (m97 structure, proven R3/R5)
__global__ __launch_bounds__(256) void k_linear(const unsigned short* __restrict__ A,
                                                const unsigned short* __restrict__ Wb,
                                                const float* __restrict__ bias,
                                                float* __restrict__ out) {
    const int bm = blockIdx.x >> 3, bn = blockIdx.x & 7;
    const int tid = threadIdx.x;
    const int w = tid >> 6, lane = tid & 63, l15 = lane & 15, hh = lane >> 4;
    const int wm = w >> 1, wn = w & 1;
    const int m0 = bm * 128, n0 = bn * 128;

    __shared__ __align__(16) unsigned short As[128 * 64];
    __shared__ __align__(16) unsigned short Bs[128 * 64];

    const int srow = lane >> 3;
    const int scol = (lane & 7) * 8;

    f32x4 acc[4][4];
#pragma unroll
    for (int i = 0; i < 4; ++i)
#pragma unroll
        for (int j = 0; j < 4; ++j) acc[i][j] = (f32x4){0.f, 0.f, 0.f, 0.f};

    for (int kt = 0; kt < 16; ++kt) {
        __syncthreads();
#pragma unroll
        for (int i = 0; i < 4; ++i) {
            const int rr = (w*4 + i)*8 + srow;
            gload16(A  + (size_t)(m0 + rr) * 1024 + kt*64 + scol, &As[(w*4 + i) * 512]);
            gload16(Wb + (size_t)(n0 + rr) * 1024 + kt*64 + scol, &Bs[(w*4 + i) * 512]);
        }
        __syncthreads();
#pragma unroll
        for (int ks = 0; ks < 2; ++ks) {
            bf16x8 af[4], bw[4];
#pragma unroll
            for (int mi = 0; mi < 4; ++mi)
                af[mi] = *(const bf16x8*)&As[(wm*64 + 16*mi + l15) * 64 + ks*32 + 8*hh];
#pragma unroll
            for (int ni = 0; ni < 4; ++ni)
                bw[ni] = *(const bf16x8*)&Bs[(wn*64 + 16*ni + l15) * 64 + ks*32 + 8*hh];
#pragma unroll
            for (int mi = 0; mi < 4; ++mi)
#pragma unroll
                for (int ni = 0; ni < 4; ++ni)
                    acc[mi][ni] = mfma16(af[mi], bw[ni], acc[mi][ni]);
        }
    }

    float bs[4];
#pragma unroll
    for (int ni = 0; ni < 4; ++ni) bs[ni] = bias[n0 + wn*64 + 16*ni + l15];
#pragma unroll
    for (int mi = 0; mi < 4; ++mi) {
        const int row = m0 + wm*64 + 16*mi + 4*hh;
#pragma unroll
        for (int r = 0; r < 4; ++r) {
            float* o = out + (size_t)(row + r) * 1024 + n0 + wn*64;
#pragma unroll
            for (int ni = 0; ni < 4; ++ni)
                o[16*ni + l15] = acc[mi][ni][r] + bs[ni];
        }
    }
}

// ------------------------------------------------------------ launch ------
extern "C" void kernel_launch(void* const* d_in, const int* in_sizes, int n_in,
                              void* d_out, int out_size, void* d_ws, size_t ws_size,
                              hipStream_t stream) {
    const float* q    = (const float*)d_in[0];
    const float* k    = (const float*)d_in[1];
    const float* v    = (const float*)d_in[2];
    const float* W    = (const float*)d_in[3];
    const float* bias = (const float*)d_in[4];
    const float* proj = (const float*)d_in[5];
    float* out = (float*)d_out;

    int nchunk = 8;
    while (nchunk > 4) {
        size_t need = 33554432ull + 2097152 + 2097152 + 65536 + 32768
                    + (size_t)nchunk * 65536
                    + (size_t)nchunk * 4194304
                    + 4096;
        if (need <= ws_size) break;
        nchunk >>= 1;
    }
    const int cshift = (nchunk == 8) ? 3 : 2;
    const int ntiles = 64 / nchunk;

    char* ws = (char*)d_ws;
    size_t off = 0;
    unsigned short* attn  = (unsigned short*)(ws + off); off += 33554432;
    unsigned short* ctxT  = (unsigned short*)(ws + off); off += 2097152;
    unsigned short* Wb    = (unsigned short*)(ws + off); off += 2097152;
    float*          ksum  = (float*)(ws + off);          off += 65536;
    unsigned short* projs = (unsigned short*)(ws + off); off += 32768;
    float*          ksump = (float*)(ws + off);          off += (size_t)nchunk * 65536;
    float*          ctxp  = (float*)(ws + off);          off += (size_t)nchunk * 4194304;

    k_prep<<<dim3(4096), dim3(256), 0, stream>>>(W, proj, Wb, projs);
    k_ctx<<<dim3(64 * nchunk), dim3(256), 0, stream>>>(k, v, projs, ctxp, ksump,
                                                       cshift, ntiles);
    k_reduce<<<dim3(64), dim3(256), 0, stream>>>(ctxp, ksump, ctxT, ksum, nchunk);
    k_qout<<<dim3(4096), dim3(256), 0, stream>>>(q, projs, ctxT, ksum, attn);
    k_linear<<<dim3(1024), dim3(256), 0, stream>>>(attn, Wb, bias, out);
}

// Round 7
// 282.086 us; speedup vs baseline: 1.1030x; 1.1030x over previous
//
#include <hip/hip_runtime.h>
#include <hip/hip_bf16.h>
#include <stdint.h>

// Problem constants: B=4, N=4096, D=1024, H=16, M=256, DH=64
#define DATA_SCALE 0.35355339059327373f  // 64^-0.25
#define DN_SCALE   0.0625f               // 0.5 * 64^-0.5

typedef __bf16 bf16x8 __attribute__((ext_vector_type(8)));
typedef float  f32x4  __attribute__((ext_vector_type(4)));

static __device__ __forceinline__ unsigned short f2bf(float f) {
    union { float f; unsigned int u; } v; v.f = f;
    unsigned int r = v.u + 0x7fffu + ((v.u >> 16) & 1u);
    return (unsigned short)(r >> 16);
}

static __device__ __forceinline__ f32x4 mfma16(bf16x8 a, bf16x8 b, f32x4 c) {
    return __builtin_amdgcn_mfma_f32_16x16x32_bf16(a, b, c, 0, 0, 0);
}

static __device__ __forceinline__ void gload16(const void* g, void* lds) {
    __builtin_amdgcn_global_load_lds(
        (const __attribute__((address_space(1))) unsigned int*)g,
        (__attribute__((address_space(3))) unsigned int*)lds, 16, 0, 0);
}

union U8 { unsigned short s[8]; bf16x8 v; };

// ---------------------------------------------------------------- prep ----
__global__ __launch_bounds__(256) void k_prep(const float* __restrict__ W,
                                              const float* __restrict__ proj,
                                              unsigned short* __restrict__ Wb,
                                              unsigned short* __restrict__ projs,
                                              unsigned short* __restrict__ projs_swz) {
    int i = blockIdx.x * 256 + threadIdx.x;
    if (i < 1024 * 1024) Wb[i] = f2bf(W[i]);
    if (i < 256 * 64) {
        const int row = i >> 6, col = i & 63;
        unsigned short v = f2bf(proj[i] * DATA_SCALE);
        projs[i] = v;
        // pre-swizzled copy for k_qout's LDS staging (rule #21: linear
        // gload16 dest + permuted source == swizzled LDS layout)
        projs_swz[row * 64 + (col ^ ((row & 7) << 3))] = v;
    }
}

// ------------------------------------------------------------- k_ctx ------
// (R6-proven) n-split S phase; ctx phase m-split; 2 barriers/tile.
__global__ __launch_bounds__(256) void k_ctx(const float* __restrict__ kg,
                                             const float* __restrict__ vg,
                                             const unsigned short* __restrict__ projs,
                                             float* __restrict__ ctx_part,
                                             float* __restrict__ ksum_part,
                                             int cshift, int ntiles) {
    const int bh = blockIdx.x >> cshift, chunk = blockIdx.x & ((1 << cshift) - 1);
    const int b = bh >> 4, h = bh & 15;
    const int tid = threadIdx.x;
    const int w = tid >> 6, lane = tid & 63, l15 = lane & 15, hh = lane >> 4;

    __shared__ __align__(16) unsigned short kpT[256][72];
    __shared__ __align__(16) unsigned short VT[64][72];

    f32x4 cacc[4][4];
#pragma unroll
    for (int i = 0; i < 4; ++i)
#pragma unroll
        for (int j = 0; j < 4; ++j) cacc[i][j] = (f32x4){0.f, 0.f, 0.f, 0.f};
    float ksacc[16];
#pragma unroll
    for (int i = 0; i < 16; ++i) ksacc[i] = 0.f;

    const size_t rowoff = (size_t)(b * 4096 + chunk * ntiles * 64) * 1024 + h * 64;

    for (int tt = 0; tt < ntiles; ++tt) {
        __syncthreads();   // A: prev tile's kpT/VT reads complete

        {
            const int n = lane, cs = w * 16;
            const float* src = vg + rowoff + (size_t)(tt*64 + n) * 1024 + cs;
#pragma unroll
            for (int j = 0; j < 16; j += 4) {
                float4 f = *(const float4*)(src + j);
                VT[cs+j+0][n] = f2bf(f.x); VT[cs+j+1][n] = f2bf(f.y);
                VT[cs+j+2][n] = f2bf(f.z); VT[cs+j+3][n] = f2bf(f.w);
            }
        }

        const float* kb = kg + rowoff + ((size_t)tt*64 + 16*w + l15) * 1024 + hh * 8;
        float4 k0 = *(const float4*)(kb);
        float4 k1 = *(const float4*)(kb + 4);
        float4 k2 = *(const float4*)(kb + 32);
        float4 k3 = *(const float4*)(kb + 36);
        float s2 = k0.x*k0.x + k0.y*k0.y + k0.z*k0.z + k0.w*k0.w
                 + k1.x*k1.x + k1.y*k1.y + k1.z*k1.z + k1.w*k1.w
                 + k2.x*k2.x + k2.y*k2.y + k2.z*k2.z + k2.w*k2.w
                 + k3.x*k3.x + k3.y*k3.y + k3.z*k3.z + k3.w*k3.w;
        s2 += __shfl_xor(s2, 16);
        s2 += __shfl_xor(s2, 32);
        U8 a0, a1;
        a0.s[0]=f2bf(k0.x); a0.s[1]=f2bf(k0.y); a0.s[2]=f2bf(k0.z); a0.s[3]=f2bf(k0.w);
        a0.s[4]=f2bf(k1.x); a0.s[5]=f2bf(k1.y); a0.s[6]=f2bf(k1.z); a0.s[7]=f2bf(k1.w);
        a1.s[0]=f2bf(k2.x); a1.s[1]=f2bf(k2.y); a1.s[2]=f2bf(k2.z); a1.s[3]=f2bf(k2.w);
        a1.s[4]=f2bf(k3.x); a1.s[5]=f2bf(k3.y); a1.s[6]=f2bf(k3.z); a1.s[7]=f2bf(k3.w);

        f32x4 sacc[16];
#pragma unroll
        for (int i = 0; i < 16; ++i) sacc[i] = (f32x4){0.f, 0.f, 0.f, 0.f};
#pragma unroll
        for (int ni = 0; ni < 16; ++ni) {
            bf16x8 pb0 = *(const bf16x8*)(projs + (size_t)(16*ni + l15) * 64 + 8*hh);
            sacc[ni] = mfma16(a0.v, pb0, sacc[ni]);
        }
#pragma unroll
        for (int ni = 0; ni < 16; ++ni) {
            bf16x8 pb1 = *(const bf16x8*)(projs + (size_t)(16*ni + l15) * 64 + 32 + 8*hh);
            sacc[ni] = mfma16(a1.v, pb1, sacc[ni]);
        }

        float pm[4];
#pragma unroll
        for (int r = 0; r < 4; ++r) {
            float m01 = fmaxf(sacc[0][r], sacc[1][r]);
#pragma unroll
            for (int ni = 2; ni < 16; ++ni) m01 = fmaxf(m01, sacc[ni][r]);
            pm[r] = m01;
        }
#pragma unroll
        for (int msk = 1; msk <= 8; msk <<= 1)
#pragma unroll
            for (int r = 0; r < 4; ++r)
                pm[r] = fmaxf(pm[r], __shfl_xor(pm[r], msk));
        float offv[4];
#pragma unroll
        for (int r = 0; r < 4; ++r) {
            float s2r = __shfl(s2, (lane & 48) + 4*hh + r);
            offv[r] = pm[r] + DN_SCALE * s2r;
        }

#pragma unroll
        for (int ni = 0; ni < 16; ++ni) {
            float e0 = __expf(sacc[ni][0] - offv[0]);
            float e1 = __expf(sacc[ni][1] - offv[1]);
            float e2 = __expf(sacc[ni][2] - offv[2]);
            float e3 = __expf(sacc[ni][3] - offv[3]);
            ksacc[ni] += e0 + e1 + e2 + e3;
            uint2 pk;
            pk.x = (unsigned int)f2bf(e0) | ((unsigned int)f2bf(e1) << 16);
            pk.y = (unsigned int)f2bf(e2) | ((unsigned int)f2bf(e3) << 16);
            const int colp = (16*w + 4*hh) ^ (8*(ni & 7));
            *(uint2*)&kpT[16*ni + l15][colp] = pk;
        }
        __syncthreads();   // B: kpT + VT ready

#pragma unroll
        for (int ks = 0; ks < 2; ++ks) {
            bf16x8 am[4], bv[4];
#pragma unroll
            for (int mi = 0; mi < 4; ++mi) {
                const int row = 64*w + 16*mi + l15;
                const int s = (4*w + mi) & 7;
                am[mi] = *(const bf16x8*)&kpT[row][8*((4*ks + hh) ^ s)];
            }
#pragma unroll
            for (int ni = 0; ni < 4; ++ni)
                bv[ni] = *(const bf16x8*)&VT[16*ni + l15][ks*32 + 8*hh];
#pragma unroll
            for (int mi = 0; mi < 4; ++mi)
#pragma unroll
                for (int ni = 0; ni < 4; ++ni)
                    cacc[mi][ni] = mfma16(am[mi], bv[ni], cacc[mi][ni]);
        }
    }

#pragma unroll
    for (int ni = 0; ni < 16; ++ni) {
        ksacc[ni] += __shfl_xor(ksacc[ni], 16);
        ksacc[ni] += __shfl_xor(ksacc[ni], 32);
    }
    __syncthreads();
    float* ksW = (float*)&VT[0][0];
    if (hh == 0) {
#pragma unroll
        for (int ni = 0; ni < 16; ++ni)
            ksW[w*256 + 16*ni + l15] = ksacc[ni];
    }
    __syncthreads();
    const int pc = blockIdx.x;
    if (tid < 256)
        ksum_part[(size_t)pc * 256 + tid] = ksW[tid] + ksW[256 + tid]
                                          + ksW[512 + tid] + ksW[768 + tid];
    float* cp = ctx_part + (size_t)pc * 256 * 64;
#pragma unroll
    for (int mi = 0; mi < 4; ++mi)
#pragma unroll
        for (int ni = 0; ni < 4; ++ni)
#pragma unroll
            for (int r = 0; r < 4; ++r)
                cp[(64*w + 16*mi + 4*hh + r) * 64 + 16*ni + l15] = cacc[mi][ni][r];
}

// ------------------------------------------------------------ reduce ------
// R7: grid = 64 bh * 4 parts (256 blocks). Each block: 64 m-rows, all 64 dh.
__global__ __launch_bounds__(256) void k_reduce(const float* __restrict__ ctx_part,
                                                const float* __restrict__ ksum_part,
                                                unsigned short* __restrict__ ctxT,
                                                float* __restrict__ ksum, int nchunk) {
    const int bh = blockIdx.x >> 2, part = blockIdx.x & 3;
    const int t = threadIdx.x;
    const int m = part*64 + (t & 63);
    const int dq = t >> 6;                       // dh quarter: 16 dh
    const float* cp = ctx_part + (size_t)bh * nchunk * 16384 + m*64 + dq*16;
    f32x4 s[4];
#pragma unroll
    for (int j = 0; j < 4; ++j) s[j] = *(const f32x4*)(cp + j*4);
    for (int c = 1; c < nchunk; ++c) {
        const float* cc = cp + (size_t)c * 16384;
#pragma unroll
        for (int j = 0; j < 4; ++j) {
            f32x4 a = *(const f32x4*)(cc + j*4);
            s[j] += a;
        }
    }
    unsigned short* ct = ctxT + (size_t)bh * 16384;
#pragma unroll
    for (int j = 0; j < 4; ++j)
#pragma unroll
        for (int e = 0; e < 4; ++e)
            ct[(dq*16 + j*4 + e) * 256 + m] = f2bf(s[j][e]);
    if (t < 64) {
        const int m2 = part*64 + t;
        const float* kp_ = ksum_part + (size_t)bh * nchunk * 256;
        float ks = 0.f;
        for (int c = 0; c < nchunk; ++c) ks += kp_[c*256 + m2];
        ksum[(size_t)bh * 256 + m2] = ks;
    }
}

// ------------------------------------------------------------- k_qout -----
// R7: grid = 64 bh * 16 (1024 blocks); each block does 4 x 64-row tiles.
// n-split (wave owns 16 rows/tile), zero per-tile barriers.
// proj staged once in LDS (swizzled), uL swizzled [16][256], Q reg-prefetch.
__global__ __launch_bounds__(256) void k_qout(const float* __restrict__ qg,
                                              const unsigned short* __restrict__ projs_swz,
                                              const unsigned short* __restrict__ ctxT,
                                              const float* __restrict__ ksum,
                                              unsigned short* __restrict__ attn) {
    const int bh = blockIdx.x >> 4, rg = blockIdx.x & 15;
    const int b = bh >> 4, h = bh & 15;
    const int tid = threadIdx.x;
    const int w = tid >> 6, lane = tid & 63, l15 = lane & 15, hh = lane >> 4;

    __shared__ __align__(16) unsigned short pjL[256 * 64];   // swizzled proj (32 KB)
    __shared__ __align__(16) unsigned short uL[4][16 * 256]; // per-wave u (32 KB)

    // ---- stage proj -> LDS (linear copy of pre-swizzled global) ----
#pragma unroll
    for (int i = 0; i < 8; ++i) {
        const int blk = i*4 + w;   // 1 KB per wave-call
        gload16((const char*)projs_swz + blk*1024 + lane*16,
                (char*)pjL + blk*1024);
    }

    float ksr[16];
#pragma unroll
    for (int ni = 0; ni < 16; ++ni)
        ksr[ni] = ksum[(size_t)bh * 256 + 16*ni + l15];

    const unsigned short* cb = ctxT + (size_t)bh * 16384;
    const float* qtile = qg + (size_t)(b*4096 + rg*256 + 16*w + l15) * 1024 + h*64 + hh*8;

    float4 qA[4], qB[4];
    qA[0] = *(const float4*)(qtile);
    qA[1] = *(const float4*)(qtile + 4);
    qA[2] = *(const float4*)(qtile + 32);
    qA[3] = *(const float4*)(qtile + 36);

    __syncthreads();   // pjL ready (drains gload16 + qA)

#pragma unroll
    for (int t = 0; t < 4; ++t) {
        const float4* qc = (t & 1) ? qB : qA;
        float4*       qn = (t & 1) ? qA : qB;

        // convert current Q to A-frags
        U8 a0, a1;
        a0.s[0]=f2bf(qc[0].x); a0.s[1]=f2bf(qc[0].y); a0.s[2]=f2bf(qc[0].z); a0.s[3]=f2bf(qc[0].w);
        a0.s[4]=f2bf(qc[1].x); a0.s[5]=f2bf(qc[1].y); a0.s[6]=f2bf(qc[1].z); a0.s[7]=f2bf(qc[1].w);
        a1.s[0]=f2bf(qc[2].x); a1.s[1]=f2bf(qc[2].y); a1.s[2]=f2bf(qc[2].z); a1.s[3]=f2bf(qc[2].w);
        a1.s[4]=f2bf(qc[3].x); a1.s[5]=f2bf(qc[3].y); a1.s[6]=f2bf(qc[3].z); a1.s[7]=f2bf(qc[3].w);

        // prefetch next tile's Q (T14: issue early, consume next iter)
        if (t < 3) {
            const float* qs = qtile + (size_t)(t + 1) * 65536;
            qn[0] = *(const float4*)(qs);
            qn[1] = *(const float4*)(qs + 4);
            qn[2] = *(const float4*)(qs + 32);
            qn[3] = *(const float4*)(qs + 36);
        }

        // ---- S_q GEMM: B-frags from swizzled LDS ----
        f32x4 sacc[16];
#pragma unroll
        for (int i = 0; i < 16; ++i) sacc[i] = (f32x4){0.f, 0.f, 0.f, 0.f};
#pragma unroll
        for (int ni = 0; ni < 16; ++ni) {
            bf16x8 pb0 = *(const bf16x8*)&pjL[(16*ni + l15)*64 + ((8*hh) ^ ((l15 & 7) << 3))];
            sacc[ni] = mfma16(a0.v, pb0, sacc[ni]);
        }
#pragma unroll
        for (int ni = 0; ni < 16; ++ni) {
            bf16x8 pb1 = *(const bf16x8*)&pjL[(16*ni + l15)*64 + ((32 + 8*hh) ^ ((l15 & 7) << 3))];
            sacc[ni] = mfma16(a1.v, pb1, sacc[ni]);
        }

        // ---- u = exp(S); den partials; swizzled uL write ----
        float dp[4] = {0.f, 0.f, 0.f, 0.f};
#pragma unroll
        for (int ni = 0; ni < 16; ++ni) {
#pragma unroll
            for (int r = 0; r < 4; ++r) {
                float e = __expf(sacc[ni][r]);
                dp[r] += e * ksr[ni];
                const int row = 4*hh + r;
                uL[w][row*256 + ((16*ni + l15) ^ ((row & 7) << 3))] = f2bf(e);
            }
        }
#pragma unroll
        for (int msk = 1; msk <= 8; msk <<= 1)
#pragma unroll
            for (int r = 0; r < 4; ++r)
                dp[r] += __shfl_xor(dp[r], msk);

        // same-wave LDS write->read ordering (rule #18)
        asm volatile("s_waitcnt lgkmcnt(0)" ::: "memory");
        __builtin_amdgcn_sched_barrier(0);

        // ---- num = u @ ctx : A from swizzled uL, B from ctxT (L2) ----
        f32x4 nacc[4];
#pragma unroll
        for (int i = 0; i < 4; ++i) nacc[i] = (f32x4){0.f, 0.f, 0.f, 0.f};
#pragma unroll
        for (int ks = 0; ks < 8; ++ks) {
            bf16x8 a = *(const bf16x8*)&uL[w][l15*256 + ((ks*32 + 8*hh) ^ ((l15 & 7) << 3))];
#pragma unroll
            for (int ni = 0; ni < 4; ++ni) {
                bf16x8 bb = *(const bf16x8*)(cb + (size_t)(16*ni + l15) * 256 + ks*32 + 8*hh);
                nacc[ni] = mfma16(a, bb, nacc[ni]);
            }
        }

        // ---- epilogue: attn = num * (1/den) ----
#pragma unroll
        for (int r = 0; r < 4; ++r) {
            const float rd = 1.f / dp[r];
            const int grow = rg*256 + t*64 + 16*w + 4*hh + r;
            unsigned short* dst = attn + (size_t)(b*4096 + grow) * 1024 + h*64;
#pragma unroll
            for (int ni = 0; ni < 4; ++ni)
                dst[16*ni + l15] = f2bf(nacc[ni][r] * rd);
        }
        __builtin_amdgcn_sched_barrier(0);  // keep tile phases ordered
    }
}

// ------------------------------------------------------------ k_linear ----
// out[16384][1024] = attn_bf16 @ Wb^T + bias  (m97 structure, proven)
__global__ __launch_bounds__(256) void k_linear(const unsigned short* __restrict__ A,
                                                const unsigned short* __restrict__ Wb,
                                                const float* __restrict__ bias,
                                                float* __restrict__ out) {
    const int bm = blockIdx.x >> 3, bn = blockIdx.x & 7;
    const int tid = threadIdx.x;
    const int w = tid >> 6, lane = tid & 63, l15 = lane & 15, hh = lane >> 4;
    const int wm = w >> 1, wn = w & 1;
    const int m0 = bm * 128, n0 = bn * 128;

    __shared__ __align__(16) unsigned short As[128 * 64];
    __shared__ __align__(16) unsigned short Bs[128 * 64];

    const int srow = lane >> 3;
    const int scol = (lane & 7) * 8;

    f32x4 acc[4][4];
#pragma unroll
    for (int i = 0; i < 4; ++i)
#pragma unroll
        for (int j = 0; j < 4; ++j) acc[i][j] = (f32x4){0.f, 0.f, 0.f, 0.f};

    for (int kt = 0; kt < 16; ++kt) {
        __syncthreads();
#pragma unroll
        for (int i = 0; i < 4; ++i) {
            const int rr = (w*4 + i)*8 + srow;
            gload16(A  + (size_t)(m0 + rr) * 1024 + kt*64 + scol, &As[(w*4 + i) * 512]);
            gload16(Wb + (size_t)(n0 + rr) * 1024 + kt*64 + scol, &Bs[(w*4 + i) * 512]);
        }
        __syncthreads();
#pragma unroll
        for (int ks = 0; ks < 2; ++ks) {
            bf16x8 af[4], bw[4];
#pragma unroll
            for (int mi = 0; mi < 4; ++mi)
                af[mi] = *(const bf16x8*)&As[(wm*64 + 16*mi + l15) * 64 + ks*32 + 8*hh];
#pragma unroll
            for (int ni = 0; ni < 4; ++ni)
                bw[ni] = *(const bf16x8*)&Bs[(wn*64 + 16*ni + l15) * 64 + ks*32 + 8*hh];
#pragma unroll
            for (int mi = 0; mi < 4; ++mi)
#pragma unroll
                for (int ni = 0; ni < 4; ++ni)
                    acc[mi][ni] = mfma16(af[mi], bw[ni], acc[mi][ni]);
        }
    }

    float bs[4];
#pragma unroll
    for (int ni = 0; ni < 4; ++ni) bs[ni] = bias[n0 + wn*64 + 16*ni + l15];
#pragma unroll
    for (int mi = 0; mi < 4; ++mi) {
        const int row = m0 + wm*64 + 16*mi + 4*hh;
#pragma unroll
        for (int r = 0; r < 4; ++r) {
            float* o = out + (size_t)(row + r) * 1024 + n0 + wn*64;
#pragma unroll
            for (int ni = 0; ni < 4; ++ni)
                o[16*ni + l15] = acc[mi][ni][r] + bs[ni];
        }
    }
}

// ------------------------------------------------------------ launch ------
extern "C" void kernel_launch(void* const* d_in, const int* in_sizes, int n_in,
                              void* d_out, int out_size, void* d_ws, size_t ws_size,
                              hipStream_t stream) {
    const float* q    = (const float*)d_in[0];
    const float* k    = (const float*)d_in[1];
    const float* v    = (const float*)d_in[2];
    const float* W    = (const float*)d_in[3];
    const float* bias = (const float*)d_in[4];
    const float* proj = (const float*)d_in[5];
    float* out = (float*)d_out;

    int nchunk = 8;
    while (nchunk > 4) {
        size_t need = 33554432ull + 2097152 + 2097152 + 65536 + 32768 + 32768
                    + (size_t)nchunk * 65536
                    + (size_t)nchunk * 4194304
                    + 4096;
        if (need <= ws_size) break;
        nchunk >>= 1;
    }
    const int cshift = (nchunk == 8) ? 3 : 2;
    const int ntiles = 64 / nchunk;

    char* ws = (char*)d_ws;
    size_t off = 0;
    unsigned short* attn  = (unsigned short*)(ws + off); off += 33554432;
    unsigned short* ctxT  = (unsigned short*)(ws + off); off += 2097152;
    unsigned short* Wb    = (unsigned short*)(ws + off); off += 2097152;
    float*          ksum  = (float*)(ws + off);          off += 65536;
    unsigned short* projs = (unsigned short*)(ws + off); off += 32768;
    unsigned short* projz = (unsigned short*)(ws + off); off += 32768;
    float*          ksump = (float*)(ws + off);          off += (size_t)nchunk * 65536;
    float*          ctxp  = (float*)(ws + off);          off += (size_t)nchunk * 4194304;

    k_prep<<<dim3(4096), dim3(256), 0, stream>>>(W, proj, Wb, projs, projz);
    k_ctx<<<dim3(64 * nchunk), dim3(256), 0, stream>>>(k, v, projs, ctxp, ksump,
                                                       cshift, ntiles);
    k_reduce<<<dim3(256), dim3(256), 0, stream>>>(ctxp, ksump, ctxT, ksum, nchunk);
    k_qout<<<dim3(1024), dim3(256), 0, stream>>>(q, projz, ctxT, ksum, attn);
    k_linear<<<dim3(1024), dim3(256), 0, stream>>>(attn, Wb, bias, out);
}

// Round 8
// 238.024 us; speedup vs baseline: 1.3072x; 1.1851x over previous
//
#include <hip/hip_runtime.h>
#include <hip/hip_bf16.h>
#include <stdint.h>

// Problem constants: B=4, N=4096, D=1024, H=16, M=256, DH=64
#define DATA_SCALE 0.35355339059327373f  // 64^-0.25
#define DN_SCALE   0.0625f               // 0.5 * 64^-0.5

typedef __bf16 bf16x8 __attribute__((ext_vector_type(8)));
typedef float  f32x4  __attribute__((ext_vector_type(4)));

static __device__ __forceinline__ unsigned short f2bf(float f) {
    union { float f; unsigned int u; } v; v.f = f;
    unsigned int r = v.u + 0x7fffu + ((v.u >> 16) & 1u);
    return (unsigned short)(r >> 16);
}

static __device__ __forceinline__ f32x4 mfma16(bf16x8 a, bf16x8 b, f32x4 c) {
    return __builtin_amdgcn_mfma_f32_16x16x32_bf16(a, b, c, 0, 0, 0);
}

static __device__ __forceinline__ void gload16(const void* g, void* lds) {
    __builtin_amdgcn_global_load_lds(
        (const __attribute__((address_space(1))) unsigned int*)g,
        (__attribute__((address_space(3))) unsigned int*)lds, 16, 0, 0);
}

union U8 { unsigned short s[8]; bf16x8 v; };

// ---------------------------------------------------------------- prep ----
__global__ __launch_bounds__(256) void k_prep(const float* __restrict__ W,
                                              const float* __restrict__ proj,
                                              unsigned short* __restrict__ Wb,
                                              unsigned short* __restrict__ projs,
                                              unsigned short* __restrict__ projs_swz) {
    int i = blockIdx.x * 256 + threadIdx.x;
    if (i < 1024 * 1024) Wb[i] = f2bf(W[i]);
    if (i < 256 * 64) {
        const int row = i >> 6, col = i & 63;
        unsigned short v = f2bf(proj[i] * DATA_SCALE);
        projs[i] = v;
        // pre-swizzled copy for LDS staging (rule #21: linear gload16 dest +
        // permuted source == swizzled LDS layout; XOR involution on read)
        projs_swz[row * 64 + (col ^ ((row & 7) << 3))] = v;
    }
}

// ------------------------------------------------------------- k_ctx ------
// n-split S phase (B-frags now from LDS-staged swizzled proj);
// ctx phase m-split; 2 barriers/tile. LDS 78.8KB -> 2 blocks/CU.
__global__ __launch_bounds__(256) void k_ctx(const float* __restrict__ kg,
                                             const float* __restrict__ vg,
                                             const unsigned short* __restrict__ projz,
                                             float* __restrict__ ctx_part,
                                             float* __restrict__ ksum_part,
                                             int cshift, int ntiles) {
    const int bh = blockIdx.x >> cshift, chunk = blockIdx.x & ((1 << cshift) - 1);
    const int b = bh >> 4, h = bh & 15;
    const int tid = threadIdx.x;
    const int w = tid >> 6, lane = tid & 63, l15 = lane & 15, hh = lane >> 4;

    __shared__ __align__(16) unsigned short kpT[256][72];
    __shared__ __align__(16) unsigned short VT[64][72];
    __shared__ __align__(16) unsigned short pjL[256 * 64];   // swizzled proj

    // ---- stage proj -> LDS once (linear copy of pre-swizzled global) ----
#pragma unroll
    for (int i = 0; i < 8; ++i) {
        const int blk = i*4 + w;
        gload16((const char*)projz + blk*1024 + lane*16, (char*)pjL + blk*1024);
    }
    // drained by first loop barrier

    f32x4 cacc[4][4];
#pragma unroll
    for (int i = 0; i < 4; ++i)
#pragma unroll
        for (int j = 0; j < 4; ++j) cacc[i][j] = (f32x4){0.f, 0.f, 0.f, 0.f};
    float ksacc[16];
#pragma unroll
    for (int i = 0; i < 16; ++i) ksacc[i] = 0.f;

    const size_t rowoff = (size_t)(b * 4096 + chunk * ntiles * 64) * 1024 + h * 64;

    for (int tt = 0; tt < ntiles; ++tt) {
        __syncthreads();   // A: prev tile's kpT/VT reads done; (tt=0: pjL ready)

        {
            const int n = lane, cs = w * 16;
            const float* src = vg + rowoff + (size_t)(tt*64 + n) * 1024 + cs;
#pragma unroll
            for (int j = 0; j < 16; j += 4) {
                float4 f = *(const float4*)(src + j);
                VT[cs+j+0][n] = f2bf(f.x); VT[cs+j+1][n] = f2bf(f.y);
                VT[cs+j+2][n] = f2bf(f.z); VT[cs+j+3][n] = f2bf(f.w);
            }
        }

        const float* kb = kg + rowoff + ((size_t)tt*64 + 16*w + l15) * 1024 + hh * 8;
        float4 k0 = *(const float4*)(kb);
        float4 k1 = *(const float4*)(kb + 4);
        float4 k2 = *(const float4*)(kb + 32);
        float4 k3 = *(const float4*)(kb + 36);
        float s2 = k0.x*k0.x + k0.y*k0.y + k0.z*k0.z + k0.w*k0.w
                 + k1.x*k1.x + k1.y*k1.y + k1.z*k1.z + k1.w*k1.w
                 + k2.x*k2.x + k2.y*k2.y + k2.z*k2.z + k2.w*k2.w
                 + k3.x*k3.x + k3.y*k3.y + k3.z*k3.z + k3.w*k3.w;
        s2 += __shfl_xor(s2, 16);
        s2 += __shfl_xor(s2, 32);
        U8 a0, a1;
        a0.s[0]=f2bf(k0.x); a0.s[1]=f2bf(k0.y); a0.s[2]=f2bf(k0.z); a0.s[3]=f2bf(k0.w);
        a0.s[4]=f2bf(k1.x); a0.s[5]=f2bf(k1.y); a0.s[6]=f2bf(k1.z); a0.s[7]=f2bf(k1.w);
        a1.s[0]=f2bf(k2.x); a1.s[1]=f2bf(k2.y); a1.s[2]=f2bf(k2.z); a1.s[3]=f2bf(k2.w);
        a1.s[4]=f2bf(k3.x); a1.s[5]=f2bf(k3.y); a1.s[6]=f2bf(k3.z); a1.s[7]=f2bf(k3.w);

        f32x4 sacc[16];
#pragma unroll
        for (int i = 0; i < 16; ++i) sacc[i] = (f32x4){0.f, 0.f, 0.f, 0.f};
#pragma unroll
        for (int ni = 0; ni < 16; ++ni) {
            bf16x8 pb0 = *(const bf16x8*)&pjL[(16*ni + l15)*64 + ((8*hh) ^ ((l15 & 7) << 3))];
            sacc[ni] = mfma16(a0.v, pb0, sacc[ni]);
        }
#pragma unroll
        for (int ni = 0; ni < 16; ++ni) {
            bf16x8 pb1 = *(const bf16x8*)&pjL[(16*ni + l15)*64 + ((32 + 8*hh) ^ ((l15 & 7) << 3))];
            sacc[ni] = mfma16(a1.v, pb1, sacc[ni]);
        }

        float pm[4];
#pragma unroll
        for (int r = 0; r < 4; ++r) {
            float m01 = fmaxf(sacc[0][r], sacc[1][r]);
#pragma unroll
            for (int ni = 2; ni < 16; ++ni) m01 = fmaxf(m01, sacc[ni][r]);
            pm[r] = m01;
        }
#pragma unroll
        for (int msk = 1; msk <= 8; msk <<= 1)
#pragma unroll
            for (int r = 0; r < 4; ++r)
                pm[r] = fmaxf(pm[r], __shfl_xor(pm[r], msk));
        float offv[4];
#pragma unroll
        for (int r = 0; r < 4; ++r) {
            float s2r = __shfl(s2, (lane & 48) + 4*hh + r);
            offv[r] = pm[r] + DN_SCALE * s2r;
        }

#pragma unroll
        for (int ni = 0; ni < 16; ++ni) {
            float e0 = __expf(sacc[ni][0] - offv[0]);
            float e1 = __expf(sacc[ni][1] - offv[1]);
            float e2 = __expf(sacc[ni][2] - offv[2]);
            float e3 = __expf(sacc[ni][3] - offv[3]);
            ksacc[ni] += e0 + e1 + e2 + e3;
            uint2 pk;
            pk.x = (unsigned int)f2bf(e0) | ((unsigned int)f2bf(e1) << 16);
            pk.y = (unsigned int)f2bf(e2) | ((unsigned int)f2bf(e3) << 16);
            const int colp = (16*w + 4*hh) ^ (8*(ni & 7));
            *(uint2*)&kpT[16*ni + l15][colp] = pk;
        }
        __syncthreads();   // B: kpT + VT ready

#pragma unroll
        for (int ks = 0; ks < 2; ++ks) {
            bf16x8 am[4], bv[4];
#pragma unroll
            for (int mi = 0; mi < 4; ++mi) {
                const int row = 64*w + 16*mi + l15;
                const int s = (4*w + mi) & 7;
                am[mi] = *(const bf16x8*)&kpT[row][8*((4*ks + hh) ^ s)];
            }
#pragma unroll
            for (int ni = 0; ni < 4; ++ni)
                bv[ni] = *(const bf16x8*)&VT[16*ni + l15][ks*32 + 8*hh];
#pragma unroll
            for (int mi = 0; mi < 4; ++mi)
#pragma unroll
                for (int ni = 0; ni < 4; ++ni)
                    cacc[mi][ni] = mfma16(am[mi], bv[ni], cacc[mi][ni]);
        }
    }

#pragma unroll
    for (int ni = 0; ni < 16; ++ni) {
        ksacc[ni] += __shfl_xor(ksacc[ni], 16);
        ksacc[ni] += __shfl_xor(ksacc[ni], 32);
    }
    __syncthreads();
    float* ksW = (float*)&VT[0][0];
    if (hh == 0) {
#pragma unroll
        for (int ni = 0; ni < 16; ++ni)
            ksW[w*256 + 16*ni + l15] = ksacc[ni];
    }
    __syncthreads();
    const int pc = blockIdx.x;
    if (tid < 256)
        ksum_part[(size_t)pc * 256 + tid] = ksW[tid] + ksW[256 + tid]
                                          + ksW[512 + tid] + ksW[768 + tid];
    float* cp = ctx_part + (size_t)pc * 256 * 64;
#pragma unroll
    for (int mi = 0; mi < 4; ++mi)
#pragma unroll
        for (int ni = 0; ni < 4; ++ni)
#pragma unroll
            for (int r = 0; r < 4; ++r)
                cp[(64*w + 16*mi + 4*hh + r) * 64 + 16*ni + l15] = cacc[mi][ni][r];
}

// ------------------------------------------------------------ reduce ------
// grid = 64 bh * 4 parts. Writes ctxT SWIZZLED: col = m ^ ((dh&7)<<3),
// so k_qout can stage it linearly and read conflict-free (rule #21).
__global__ __launch_bounds__(256) void k_reduce(const float* __restrict__ ctx_part,
                                                const float* __restrict__ ksum_part,
                                                unsigned short* __restrict__ ctxT,
                                                float* __restrict__ ksum, int nchunk) {
    const int bh = blockIdx.x >> 2, part = blockIdx.x & 3;
    const int t = threadIdx.x;
    const int m = part*64 + (t & 63);
    const int dq = t >> 6;
    const float* cp = ctx_part + (size_t)bh * nchunk * 16384 + m*64 + dq*16;
    f32x4 s[4];
#pragma unroll
    for (int j = 0; j < 4; ++j) s[j] = *(const f32x4*)(cp + j*4);
    for (int c = 1; c < nchunk; ++c) {
        const float* cc = cp + (size_t)c * 16384;
#pragma unroll
        for (int j = 0; j < 4; ++j) {
            f32x4 a = *(const f32x4*)(cc + j*4);
            s[j] += a;
        }
    }
    unsigned short* ct = ctxT + (size_t)bh * 16384;
#pragma unroll
    for (int j = 0; j < 4; ++j)
#pragma unroll
        for (int e = 0; e < 4; ++e) {
            const int dh = dq*16 + j*4 + e;
            ct[dh * 256 + (m ^ ((dh & 7) << 3))] = f2bf(s[j][e]);
        }
    if (t < 64) {
        const int m2 = part*64 + t;
        const float* kp_ = ksum_part + (size_t)bh * nchunk * 256;
        float ks = 0.f;
        for (int c = 0; c < nchunk; ++c) ks += kp_[c*256 + m2];
        ksum[(size_t)bh * 256 + m2] = ks;
    }
}

// ------------------------------------------------------------- k_qout -----
// grid = 64 bh * 16 (1024 blocks); 4 x 64-row tiles/block; n-split, zero
// per-tile barriers. ALL MFMA B-operands from LDS: pjL (proj, swizzled),
// ctxL (this bh's ctx^T, swizzled), uL (u, swizzled). LDS 96KB (1 block/CU).
__global__ __launch_bounds__(256) void k_qout(const float* __restrict__ qg,
                                              const unsigned short* __restrict__ projs_swz,
                                              const unsigned short* __restrict__ ctxT,
                                              const float* __restrict__ ksum,
                                              unsigned short* __restrict__ attn) {
    const int bh = blockIdx.x >> 4, rg = blockIdx.x & 15;
    const int b = bh >> 4, h = bh & 15;
    const int tid = threadIdx.x;
    const int w = tid >> 6, lane = tid & 63, l15 = lane & 15, hh = lane >> 4;

    __shared__ __align__(16) unsigned short pjL[256 * 64];   // 32 KB
    __shared__ __align__(16) unsigned short ctxL[64 * 256];  // 32 KB
    __shared__ __align__(16) unsigned short uL[4][16 * 256]; // 32 KB

    // ---- stage proj + ctx^T -> LDS (linear copies of swizzled globals) ----
#pragma unroll
    for (int i = 0; i < 8; ++i) {
        const int blk = i*4 + w;
        gload16((const char*)projs_swz + blk*1024 + lane*16, (char*)pjL + blk*1024);
        gload16((const char*)(ctxT + (size_t)bh * 16384) + blk*1024 + lane*16,
                (char*)ctxL + blk*1024);
    }

    float ksr[16];
#pragma unroll
    for (int ni = 0; ni < 16; ++ni)
        ksr[ni] = ksum[(size_t)bh * 256 + 16*ni + l15];

    const float* qtile = qg + (size_t)(b*4096 + rg*256 + 16*w + l15) * 1024 + h*64 + hh*8;

    float4 qA[4], qB[4];
    qA[0] = *(const float4*)(qtile);
    qA[1] = *(const float4*)(qtile + 4);
    qA[2] = *(const float4*)(qtile + 32);
    qA[3] = *(const float4*)(qtile + 36);

    __syncthreads();   // pjL + ctxL ready (drains gload16)

#pragma unroll
    for (int t = 0; t < 4; ++t) {
        const float4* qc = (t & 1) ? qB : qA;
        float4*       qn = (t & 1) ? qA : qB;

        U8 a0, a1;
        a0.s[0]=f2bf(qc[0].x); a0.s[1]=f2bf(qc[0].y); a0.s[2]=f2bf(qc[0].z); a0.s[3]=f2bf(qc[0].w);
        a0.s[4]=f2bf(qc[1].x); a0.s[5]=f2bf(qc[1].y); a0.s[6]=f2bf(qc[1].z); a0.s[7]=f2bf(qc[1].w);
        a1.s[0]=f2bf(qc[2].x); a1.s[1]=f2bf(qc[2].y); a1.s[2]=f2bf(qc[2].z); a1.s[3]=f2bf(qc[2].w);
        a1.s[4]=f2bf(qc[3].x); a1.s[5]=f2bf(qc[3].y); a1.s[6]=f2bf(qc[3].z); a1.s[7]=f2bf(qc[3].w);

        if (t < 3) {
            const float* qs = qtile + (size_t)(t + 1) * 65536;
            qn[0] = *(const float4*)(qs);
            qn[1] = *(const float4*)(qs + 4);
            qn[2] = *(const float4*)(qs + 32);
            qn[3] = *(const float4*)(qs + 36);
        }

        // ---- S_q GEMM: B-frags from swizzled pjL ----
        f32x4 sacc[16];
#pragma unroll
        for (int i = 0; i < 16; ++i) sacc[i] = (f32x4){0.f, 0.f, 0.f, 0.f};
#pragma unroll
        for (int ni = 0; ni < 16; ++ni) {
            bf16x8 pb0 = *(const bf16x8*)&pjL[(16*ni + l15)*64 + ((8*hh) ^ ((l15 & 7) << 3))];
            sacc[ni] = mfma16(a0.v, pb0, sacc[ni]);
        }
#pragma unroll
        for (int ni = 0; ni < 16; ++ni) {
            bf16x8 pb1 = *(const bf16x8*)&pjL[(16*ni + l15)*64 + ((32 + 8*hh) ^ ((l15 & 7) << 3))];
            sacc[ni] = mfma16(a1.v, pb1, sacc[ni]);
        }

        // ---- u = exp(S); den partials; swizzled uL write ----
        float dp[4] = {0.f, 0.f, 0.f, 0.f};
#pragma unroll
        for (int ni = 0; ni < 16; ++ni) {
#pragma unroll
            for (int r = 0; r < 4; ++r) {
                float e = __expf(sacc[ni][r]);
                dp[r] += e * ksr[ni];
                const int row = 4*hh + r;
                uL[w][row*256 + ((16*ni + l15) ^ ((row & 7) << 3))] = f2bf(e);
            }
        }
#pragma unroll
        for (int msk = 1; msk <= 8; msk <<= 1)
#pragma unroll
            for (int r = 0; r < 4; ++r)
                dp[r] += __shfl_xor(dp[r], msk);

        // same-wave LDS write->read ordering (rule #18)
        asm volatile("s_waitcnt lgkmcnt(0)" ::: "memory");
        __builtin_amdgcn_sched_barrier(0);

        // ---- num = u @ ctx : A from uL, B from ctxL (all LDS) ----
        f32x4 nacc[4];
#pragma unroll
        for (int i = 0; i < 4; ++i) nacc[i] = (f32x4){0.f, 0.f, 0.f, 0.f};
#pragma unroll
        for (int ks = 0; ks < 8; ++ks) {
            bf16x8 a = *(const bf16x8*)&uL[w][l15*256 + ((ks*32 + 8*hh) ^ ((l15 & 7) << 3))];
#pragma unroll
            for (int ni = 0; ni < 4; ++ni) {
                bf16x8 bb = *(const bf16x8*)&ctxL[(16*ni + l15)*256
                                                  + ((ks*32 + 8*hh) ^ ((l15 & 7) << 3))];
                nacc[ni] = mfma16(a, bb, nacc[ni]);
            }
        }

        // ---- epilogue: attn = num * (1/den) ----
#pragma unroll
        for (int r = 0; r < 4; ++r) {
            const float rd = 1.f / dp[r];
            const int grow = rg*256 + t*64 + 16*w + 4*hh + r;
            unsigned short* dst = attn + (size_t)(b*4096 + grow) * 1024 + h*64;
#pragma unroll
            for (int ni = 0; ni < 4; ++ni)
                dst[16*ni + l15] = f2bf(nacc[ni][r] * rd);
        }
        __builtin_amdgcn_sched_barrier(0);  // keep tile phases ordered
    }
}

// ------------------------------------------------------------ k_linear ----
// out[16384][1024] = attn_bf16 @ Wb^T + bias  (m97 structure, proven)
__global__ __launch_bounds__(256) void k_linear(const unsigned short* __restrict__ A,
                                                const unsigned short* __restrict__ Wb,
                                                const float* __restrict__ bias,
                                                float* __restrict__ out) {
    const int bm = blockIdx.x >> 3, bn = blockIdx.x & 7;
    const int tid = threadIdx.x;
    const int w = tid >> 6, lane = tid & 63, l15 = lane & 15, hh = lane >> 4;
    const int wm = w >> 1, wn = w & 1;
    const int m0 = bm * 128, n0 = bn * 128;

    __shared__ __align__(16) unsigned short As[128 * 64];
    __shared__ __align__(16) unsigned short Bs[128 * 64];

    const int srow = lane >> 3;
    const int scol = (lane & 7) * 8;

    f32x4 acc[4][4];
#pragma unroll
    for (int i = 0; i < 4; ++i)
#pragma unroll
        for (int j = 0; j < 4; ++j) acc[i][j] = (f32x4){0.f, 0.f, 0.f, 0.f};

    for (int kt = 0; kt < 16; ++kt) {
        __syncthreads();
#pragma unroll
        for (int i = 0; i < 4; ++i) {
            const int rr = (w*4 + i)*8 + srow;
            gload16(A  + (size_t)(m0 + rr) * 1024 + kt*64 + scol, &As[(w*4 + i) * 512]);
            gload16(Wb + (size_t)(n0 + rr) * 1024 + kt*64 + scol, &Bs[(w*4 + i) * 512]);
        }
        __syncthreads();
#pragma unroll
        for (int ks = 0; ks < 2; ++ks) {
            bf16x8 af[4], bw[4];
#pragma unroll
            for (int mi = 0; mi < 4; ++mi)
                af[mi] = *(const bf16x8*)&As[(wm*64 + 16*mi + l15) * 64 + ks*32 + 8*hh];
#pragma unroll
            for (int ni = 0; ni < 4; ++ni)
                bw[ni] = *(const bf16x8*)&Bs[(wn*64 + 16*ni + l15) * 64 + ks*32 + 8*hh];
#pragma unroll
            for (int mi = 0; mi < 4; ++mi)
#pragma unroll
                for (int ni = 0; ni < 4; ++ni)
                    acc[mi][ni] = mfma16(af[mi], bw[ni], acc[mi][ni]);
        }
    }

    float bs[4];
#pragma unroll
    for (int ni = 0; ni < 4; ++ni) bs[ni] = bias[n0 + wn*64 + 16*ni + l15];
#pragma unroll
    for (int mi = 0; mi < 4; ++mi) {
        const int row = m0 + wm*64 + 16*mi + 4*hh;
#pragma unroll
        for (int r = 0; r < 4; ++r) {
            float* o = out + (size_t)(row + r) * 1024 + n0 + wn*64;
#pragma unroll
            for (int ni = 0; ni < 4; ++ni)
                o[16*ni + l15] = acc[mi][ni][r] + bs[ni];
        }
    }
}

// ------------------------------------------------------------ launch ------
extern "C" void kernel_launch(void* const* d_in, const int* in_sizes, int n_in,
                              void* d_out, int out_size, void* d_ws, size_t ws_size,
                              hipStream_t stream) {
    const float* q    = (const float*)d_in[0];
    const float* k    = (const float*)d_in[1];
    const float* v    = (const float*)d_in[2];
    const float* W    = (const float*)d_in[3];
    const float* bias = (const float*)d_in[4];
    const float* proj = (const float*)d_in[5];
    float* out = (float*)d_out;

    int nchunk = 8;
    while (nchunk > 4) {
        size_t need = 33554432ull + 2097152 + 2097152 + 65536 + 32768 + 32768
                    + (size_t)nchunk * 65536
                    + (size_t)nchunk * 4194304
                    + 4096;
        if (need <= ws_size) break;
        nchunk >>= 1;
    }
    const int cshift = (nchunk == 8) ? 3 : 2;
    const int ntiles = 64 / nchunk;

    char* ws = (char*)d_ws;
    size_t off = 0;
    unsigned short* attn  = (unsigned short*)(ws + off); off += 33554432;
    unsigned short* ctxT  = (unsigned short*)(ws + off); off += 2097152;
    unsigned short* Wb    = (unsigned short*)(ws + off); off += 2097152;
    float*          ksum  = (float*)(ws + off);          off += 65536;
    unsigned short* projs = (unsigned short*)(ws + off); off += 32768;
    unsigned short* projz = (unsigned short*)(ws + off); off += 32768;
    float*          ksump = (float*)(ws + off);          off += (size_t)nchunk * 65536;
    float*          ctxp  = (float*)(ws + off);          off += (size_t)nchunk * 4194304;

    k_prep<<<dim3(4096), dim3(256), 0, stream>>>(W, proj, Wb, projs, projz);
    k_ctx<<<dim3(64 * nchunk), dim3(256), 0, stream>>>(k, v, projz, ctxp, ksump,
                                                       cshift, ntiles);
    k_reduce<<<dim3(256), dim3(256), 0, stream>>>(ctxp, ksump, ctxT, ksum, nchunk);
    k_qout<<<dim3(1024), dim3(256), 0, stream>>>(q, projz, ctxT, ksum, attn);
    k_linear<<<dim3(1024), dim3(256), 0, stream>>>(attn, Wb, bias, out);
}

// Round 9
// 203.478 us; speedup vs baseline: 1.5292x; 1.1698x over previous
//
#include <hip/hip_runtime.h>
#include <hip/hip_bf16.h>
#include <stdint.h>

// Problem constants: B=4, N=4096, D=1024, H=16, M=256, DH=64
#define DATA_SCALE 0.35355339059327373f  // 64^-0.25
#define DN_SCALE   0.0625f               // 0.5 * 64^-0.5

typedef __bf16 bf16x8 __attribute__((ext_vector_type(8)));
typedef float  f32x4  __attribute__((ext_vector_type(4)));

static __device__ __forceinline__ unsigned short f2bf(float f) {
    union { float f; unsigned int u; } v; v.f = f;
    unsigned int r = v.u + 0x7fffu + ((v.u >> 16) & 1u);
    return (unsigned short)(r >> 16);
}

static __device__ __forceinline__ f32x4 mfma16(bf16x8 a, bf16x8 b, f32x4 c) {
    return __builtin_amdgcn_mfma_f32_16x16x32_bf16(a, b, c, 0, 0, 0);
}

static __device__ __forceinline__ void gload16(const void* g, void* lds) {
    __builtin_amdgcn_global_load_lds(
        (const __attribute__((address_space(1))) unsigned int*)g,
        (__attribute__((address_space(3))) unsigned int*)lds, 16, 0, 0);
}

union U8 { unsigned short s[8]; bf16x8 v; };

// ---------------------------------------------------------------- prep ----
__global__ __launch_bounds__(256) void k_prep(const float* __restrict__ W,
                                              const float* __restrict__ proj,
                                              unsigned short* __restrict__ Wb,
                                              unsigned short* __restrict__ projs,
                                              unsigned short* __restrict__ projs_swz) {
    int i = blockIdx.x * 256 + threadIdx.x;
    if (i < 1024 * 1024) Wb[i] = f2bf(W[i]);
    if (i < 256 * 64) {
        const int row = i >> 6, col = i & 63;
        unsigned short v = f2bf(proj[i] * DATA_SCALE);
        projs[i] = v;
        // pre-swizzled copy for LDS staging (rule #21: linear gload16 dest +
        // permuted source == swizzled LDS layout; XOR involution on read)
        projs_swz[row * 64 + (col ^ ((row & 7) << 3))] = v;
    }
}

// ------------------------------------------------------------- k_ctx ------
// R9: same math/barriers as R8, ONE change: K/V register prefetch one tile
// ahead (T14 issue-early/consume-late). Loads for tile t+1 are issued right
// after tile t's staging consumes the previous registers; the barrier-B
// vmcnt drain then finds them already complete -> HBM latency hidden under
// the S-GEMM/exp phase instead of sitting in the per-tile serial chain.
__global__ __launch_bounds__(256) void k_ctx(const float* __restrict__ kg,
                                             const float* __restrict__ vg,
                                             const unsigned short* __restrict__ projz,
                                             float* __restrict__ ctx_part,
                                             float* __restrict__ ksum_part,
                                             int cshift, int ntiles) {
    const int bh = blockIdx.x >> cshift, chunk = blockIdx.x & ((1 << cshift) - 1);
    const int b = bh >> 4, h = bh & 15;
    const int tid = threadIdx.x;
    const int w = tid >> 6, lane = tid & 63, l15 = lane & 15, hh = lane >> 4;

    __shared__ __align__(16) unsigned short kpT[256][72];
    __shared__ __align__(16) unsigned short VT[64][72];
    __shared__ __align__(16) unsigned short pjL[256 * 64];   // swizzled proj

    // ---- stage proj -> LDS once (linear copy of pre-swizzled global) ----
#pragma unroll
    for (int i = 0; i < 8; ++i) {
        const int blk = i*4 + w;
        gload16((const char*)projz + blk*1024 + lane*16, (char*)pjL + blk*1024);
    }
    // drained by first loop barrier

    f32x4 cacc[4][4];
#pragma unroll
    for (int i = 0; i < 4; ++i)
#pragma unroll
        for (int j = 0; j < 4; ++j) cacc[i][j] = (f32x4){0.f, 0.f, 0.f, 0.f};
    float ksacc[16];
#pragma unroll
    for (int i = 0; i < 16; ++i) ksacc[i] = 0.f;

    const size_t rowoff = (size_t)(b * 4096 + chunk * ntiles * 64) * 1024 + h * 64;

    // per-thread fixed source addresses (tile offset added per iteration)
    const float* vbase = vg + rowoff + (size_t)lane * 1024 + w * 16;
    const float* kbase = kg + rowoff + (size_t)(16*w + l15) * 1024 + hh * 8;

    // ---- prologue: prefetch tile 0 into registers ----
    float4 v0 = *(const float4*)(vbase);
    float4 v1 = *(const float4*)(vbase + 4);
    float4 v2 = *(const float4*)(vbase + 8);
    float4 v3 = *(const float4*)(vbase + 12);
    float4 k0 = *(const float4*)(kbase);
    float4 k1 = *(const float4*)(kbase + 4);
    float4 k2 = *(const float4*)(kbase + 32);
    float4 k3 = *(const float4*)(kbase + 36);

    for (int tt = 0; tt < ntiles; ++tt) {
        __syncthreads();   // A: prev tile's kpT/VT reads done; (tt=0: pjL ready)

        // ---- stage VT from prefetched V registers ----
        {
            const int n = lane, cs = w * 16;
            VT[cs+ 0][n] = f2bf(v0.x); VT[cs+ 1][n] = f2bf(v0.y);
            VT[cs+ 2][n] = f2bf(v0.z); VT[cs+ 3][n] = f2bf(v0.w);
            VT[cs+ 4][n] = f2bf(v1.x); VT[cs+ 5][n] = f2bf(v1.y);
            VT[cs+ 6][n] = f2bf(v1.z); VT[cs+ 7][n] = f2bf(v1.w);
            VT[cs+ 8][n] = f2bf(v2.x); VT[cs+ 9][n] = f2bf(v2.y);
            VT[cs+10][n] = f2bf(v2.z); VT[cs+11][n] = f2bf(v2.w);
            VT[cs+12][n] = f2bf(v3.x); VT[cs+13][n] = f2bf(v3.y);
            VT[cs+14][n] = f2bf(v3.z); VT[cs+15][n] = f2bf(v3.w);
        }

        // ---- K frags + s2 from prefetched K registers ----
        float s2 = k0.x*k0.x + k0.y*k0.y + k0.z*k0.z + k0.w*k0.w
                 + k1.x*k1.x + k1.y*k1.y + k1.z*k1.z + k1.w*k1.w
                 + k2.x*k2.x + k2.y*k2.y + k2.z*k2.z + k2.w*k2.w
                 + k3.x*k3.x + k3.y*k3.y + k3.z*k3.z + k3.w*k3.w;
        s2 += __shfl_xor(s2, 16);
        s2 += __shfl_xor(s2, 32);
        U8 a0, a1;
        a0.s[0]=f2bf(k0.x); a0.s[1]=f2bf(k0.y); a0.s[2]=f2bf(k0.z); a0.s[3]=f2bf(k0.w);
        a0.s[4]=f2bf(k1.x); a0.s[5]=f2bf(k1.y); a0.s[6]=f2bf(k1.z); a0.s[7]=f2bf(k1.w);
        a1.s[0]=f2bf(k2.x); a1.s[1]=f2bf(k2.y); a1.s[2]=f2bf(k2.z); a1.s[3]=f2bf(k2.w);
        a1.s[4]=f2bf(k3.x); a1.s[5]=f2bf(k3.y); a1.s[6]=f2bf(k3.z); a1.s[7]=f2bf(k3.w);

        // ---- issue NEXT tile's K/V loads (in flight across S-GEMM/exp) ----
        if (tt + 1 < ntiles) {
            const float* vs = vbase + (size_t)(tt + 1) * 65536;
            v0 = *(const float4*)(vs);
            v1 = *(const float4*)(vs + 4);
            v2 = *(const float4*)(vs + 8);
            v3 = *(const float4*)(vs + 12);
            const float* ks_ = kbase + (size_t)(tt + 1) * 65536;
            k0 = *(const float4*)(ks_);
            k1 = *(const float4*)(ks_ + 4);
            k2 = *(const float4*)(ks_ + 32);
            k3 = *(const float4*)(ks_ + 36);
        }

        // ---- S = K @ proj^T : wave's 16 rows x all 256 m ----
        f32x4 sacc[16];
#pragma unroll
        for (int i = 0; i < 16; ++i) sacc[i] = (f32x4){0.f, 0.f, 0.f, 0.f};
#pragma unroll
        for (int ni = 0; ni < 16; ++ni) {
            bf16x8 pb0 = *(const bf16x8*)&pjL[(16*ni + l15)*64 + ((8*hh) ^ ((l15 & 7) << 3))];
            sacc[ni] = mfma16(a0.v, pb0, sacc[ni]);
        }
#pragma unroll
        for (int ni = 0; ni < 16; ++ni) {
            bf16x8 pb1 = *(const bf16x8*)&pjL[(16*ni + l15)*64 + ((32 + 8*hh) ^ ((l15 & 7) << 3))];
            sacc[ni] = mfma16(a1.v, pb1, sacc[ni]);
        }

        float pm[4];
#pragma unroll
        for (int r = 0; r < 4; ++r) {
            float m01 = fmaxf(sacc[0][r], sacc[1][r]);
#pragma unroll
            for (int ni = 2; ni < 16; ++ni) m01 = fmaxf(m01, sacc[ni][r]);
            pm[r] = m01;
        }
#pragma unroll
        for (int msk = 1; msk <= 8; msk <<= 1)
#pragma unroll
            for (int r = 0; r < 4; ++r)
                pm[r] = fmaxf(pm[r], __shfl_xor(pm[r], msk));
        float offv[4];
#pragma unroll
        for (int r = 0; r < 4; ++r) {
            float s2r = __shfl(s2, (lane & 48) + 4*hh + r);
            offv[r] = pm[r] + DN_SCALE * s2r;
        }

#pragma unroll
        for (int ni = 0; ni < 16; ++ni) {
            float e0 = __expf(sacc[ni][0] - offv[0]);
            float e1 = __expf(sacc[ni][1] - offv[1]);
            float e2 = __expf(sacc[ni][2] - offv[2]);
            float e3 = __expf(sacc[ni][3] - offv[3]);
            ksacc[ni] += e0 + e1 + e2 + e3;
            uint2 pk;
            pk.x = (unsigned int)f2bf(e0) | ((unsigned int)f2bf(e1) << 16);
            pk.y = (unsigned int)f2bf(e2) | ((unsigned int)f2bf(e3) << 16);
            const int colp = (16*w + 4*hh) ^ (8*(ni & 7));
            *(uint2*)&kpT[16*ni + l15][colp] = pk;
        }
        __syncthreads();   // B: kpT + VT ready (t+1 loads long since landed)

#pragma unroll
        for (int ks = 0; ks < 2; ++ks) {
            bf16x8 am[4], bv[4];
#pragma unroll
            for (int mi = 0; mi < 4; ++mi) {
                const int row = 64*w + 16*mi + l15;
                const int s = (4*w + mi) & 7;
                am[mi] = *(const bf16x8*)&kpT[row][8*((4*ks + hh) ^ s)];
            }
#pragma unroll
            for (int ni = 0; ni < 4; ++ni)
                bv[ni] = *(const bf16x8*)&VT[16*ni + l15][ks*32 + 8*hh];
#pragma unroll
            for (int mi = 0; mi < 4; ++mi)
#pragma unroll
                for (int ni = 0; ni < 4; ++ni)
                    cacc[mi][ni] = mfma16(am[mi], bv[ni], cacc[mi][ni]);
        }
    }

#pragma unroll
    for (int ni = 0; ni < 16; ++ni) {
        ksacc[ni] += __shfl_xor(ksacc[ni], 16);
        ksacc[ni] += __shfl_xor(ksacc[ni], 32);
    }
    __syncthreads();
    float* ksW = (float*)&VT[0][0];
    if (hh == 0) {
#pragma unroll
        for (int ni = 0; ni < 16; ++ni)
            ksW[w*256 + 16*ni + l15] = ksacc[ni];
    }
    __syncthreads();
    const int pc = blockIdx.x;
    if (tid < 256)
        ksum_part[(size_t)pc * 256 + tid] = ksW[tid] + ksW[256 + tid]
                                          + ksW[512 + tid] + ksW[768 + tid];
    float* cp = ctx_part + (size_t)pc * 256 * 64;
#pragma unroll
    for (int mi = 0; mi < 4; ++mi)
#pragma unroll
        for (int ni = 0; ni < 4; ++ni)
#pragma unroll
            for (int r = 0; r < 4; ++r)
                cp[(64*w + 16*mi + 4*hh + r) * 64 + 16*ni + l15] = cacc[mi][ni][r];
}

// ------------------------------------------------------------ reduce ------
// grid = 64 bh * 4 parts. Writes ctxT SWIZZLED: col = m ^ ((dh&7)<<3),
// so k_qout can stage it linearly and read conflict-free (rule #21).
__global__ __launch_bounds__(256) void k_reduce(const float* __restrict__ ctx_part,
                                                const float* __restrict__ ksum_part,
                                                unsigned short* __restrict__ ctxT,
                                                float* __restrict__ ksum, int nchunk) {
    const int bh = blockIdx.x >> 2, part = blockIdx.x & 3;
    const int t = threadIdx.x;
    const int m = part*64 + (t & 63);
    const int dq = t >> 6;
    const float* cp = ctx_part + (size_t)bh * nchunk * 16384 + m*64 + dq*16;
    f32x4 s[4];
#pragma unroll
    for (int j = 0; j < 4; ++j) s[j] = *(const f32x4*)(cp + j*4);
    for (int c = 1; c < nchunk; ++c) {
        const float* cc = cp + (size_t)c * 16384;
#pragma unroll
        for (int j = 0; j < 4; ++j) {
            f32x4 a = *(const f32x4*)(cc + j*4);
            s[j] += a;
        }
    }
    unsigned short* ct = ctxT + (size_t)bh * 16384;
#pragma unroll
    for (int j = 0; j < 4; ++j)
#pragma unroll
        for (int e = 0; e < 4; ++e) {
            const int dh = dq*16 + j*4 + e;
            ct[dh * 256 + (m ^ ((dh & 7) << 3))] = f2bf(s[j][e]);
        }
    if (t < 64) {
        const int m2 = part*64 + t;
        const float* kp_ = ksum_part + (size_t)bh * nchunk * 256;
        float ks = 0.f;
        for (int c = 0; c < nchunk; ++c) ks += kp_[c*256 + m2];
        ksum[(size_t)bh * 256 + m2] = ks;
    }
}

// ------------------------------------------------------------- k_qout -----
// grid = 64 bh * 16 (1024 blocks); 4 x 64-row tiles/block; n-split, zero
// per-tile barriers. ALL MFMA B-operands from LDS: pjL (proj, swizzled),
// ctxL (this bh's ctx^T, swizzled), uL (u, swizzled). LDS 96KB (1 block/CU).
__global__ __launch_bounds__(256) void k_qout(const float* __restrict__ qg,
                                              const unsigned short* __restrict__ projs_swz,
                                              const unsigned short* __restrict__ ctxT,
                                              const float* __restrict__ ksum,
                                              unsigned short* __restrict__ attn) {
    const int bh = blockIdx.x >> 4, rg = blockIdx.x & 15;
    const int b = bh >> 4, h = bh & 15;
    const int tid = threadIdx.x;
    const int w = tid >> 6, lane = tid & 63, l15 = lane & 15, hh = lane >> 4;

    __shared__ __align__(16) unsigned short pjL[256 * 64];   // 32 KB
    __shared__ __align__(16) unsigned short ctxL[64 * 256];  // 32 KB
    __shared__ __align__(16) unsigned short uL[4][16 * 256]; // 32 KB

    // ---- stage proj + ctx^T -> LDS (linear copies of swizzled globals) ----
#pragma unroll
    for (int i = 0; i < 8; ++i) {
        const int blk = i*4 + w;
        gload16((const char*)projs_swz + blk*1024 + lane*16, (char*)pjL + blk*1024);
        gload16((const char*)(ctxT + (size_t)bh * 16384) + blk*1024 + lane*16,
                (char*)ctxL + blk*1024);
    }

    float ksr[16];
#pragma unroll
    for (int ni = 0; ni < 16; ++ni)
        ksr[ni] = ksum[(size_t)bh * 256 + 16*ni + l15];

    const float* qtile = qg + (size_t)(b*4096 + rg*256 + 16*w + l15) * 1024 + h*64 + hh*8;

    float4 qA[4], qB[4];
    qA[0] = *(const float4*)(qtile);
    qA[1] = *(const float4*)(qtile + 4);
    qA[2] = *(const float4*)(qtile + 32);
    qA[3] = *(const float4*)(qtile + 36);

    __syncthreads();   // pjL + ctxL ready (drains gload16)

#pragma unroll
    for (int t = 0; t < 4; ++t) {
        const float4* qc = (t & 1) ? qB : qA;
        float4*       qn = (t & 1) ? qA : qB;

        U8 a0, a1;
        a0.s[0]=f2bf(qc[0].x); a0.s[1]=f2bf(qc[0].y); a0.s[2]=f2bf(qc[0].z); a0.s[3]=f2bf(qc[0].w);
        a0.s[4]=f2bf(qc[1].x); a0.s[5]=f2bf(qc[1].y); a0.s[6]=f2bf(qc[1].z); a0.s[7]=f2bf(qc[1].w);
        a1.s[0]=f2bf(qc[2].x); a1.s[1]=f2bf(qc[2].y); a1.s[2]=f2bf(qc[2].z); a1.s[3]=f2bf(qc[2].w);
        a1.s[4]=f2bf(qc[3].x); a1.s[5]=f2bf(qc[3].y); a1.s[6]=f2bf(qc[3].z); a1.s[7]=f2bf(qc[3].w);

        if (t < 3) {
            const float* qs = qtile + (size_t)(t + 1) * 65536;
            qn[0] = *(const float4*)(qs);
            qn[1] = *(const float4*)(qs + 4);
            qn[2] = *(const float4*)(qs + 32);
            qn[3] = *(const float4*)(qs + 36);
        }

        // ---- S_q GEMM: B-frags from swizzled pjL ----
        f32x4 sacc[16];
#pragma unroll
        for (int i = 0; i < 16; ++i) sacc[i] = (f32x4){0.f, 0.f, 0.f, 0.f};
#pragma unroll
        for (int ni = 0; ni < 16; ++ni) {
            bf16x8 pb0 = *(const bf16x8*)&pjL[(16*ni + l15)*64 + ((8*hh) ^ ((l15 & 7) << 3))];
            sacc[ni] = mfma16(a0.v, pb0, sacc[ni]);
        }
#pragma unroll
        for (int ni = 0; ni < 16; ++ni) {
            bf16x8 pb1 = *(const bf16x8*)&pjL[(16*ni + l15)*64 + ((32 + 8*hh) ^ ((l15 & 7) << 3))];
            sacc[ni] = mfma16(a1.v, pb1, sacc[ni]);
        }

        // ---- u = exp(S); den partials; swizzled uL write ----
        float dp[4] = {0.f, 0.f, 0.f, 0.f};
#pragma unroll
        for (int ni = 0; ni < 16; ++ni) {
#pragma unroll
            for (int r = 0; r < 4; ++r) {
                float e = __expf(sacc[ni][r]);
                dp[r] += e * ksr[ni];
                const int row = 4*hh + r;
                uL[w][row*256 + ((16*ni + l15) ^ ((row & 7) << 3))] = f2bf(e);
            }
        }
#pragma unroll
        for (int msk = 1; msk <= 8; msk <<= 1)
#pragma unroll
            for (int r = 0; r < 4; ++r)
                dp[r] += __shfl_xor(dp[r], msk);

        // same-wave LDS write->read ordering (rule #18)
        asm volatile("s_waitcnt lgkmcnt(0)" ::: "memory");
        __builtin_amdgcn_sched_barrier(0);

        // ---- num = u @ ctx : A from uL, B from ctxL (all LDS) ----
        f32x4 nacc[4];
#pragma unroll
        for (int i = 0; i < 4; ++i) nacc[i] = (f32x4){0.f, 0.f, 0.f, 0.f};
#pragma unroll
        for (int ks = 0; ks < 8; ++ks) {
            bf16x8 a = *(const bf16x8*)&uL[w][l15*256 + ((ks*32 + 8*hh) ^ ((l15 & 7) << 3))];
#pragma unroll
            for (int ni = 0; ni < 4; ++ni) {
                bf16x8 bb = *(const bf16x8*)&ctxL[(16*ni + l15)*256
                                                  + ((ks*32 + 8*hh) ^ ((l15 & 7) << 3))];
                nacc[ni] = mfma16(a, bb, nacc[ni]);
            }
        }

        // ---- epilogue: attn = num * (1/den) ----
#pragma unroll
        for (int r = 0; r < 4; ++r) {
            const float rd = 1.f / dp[r];
            const int grow = rg*256 + t*64 + 16*w + 4*hh + r;
            unsigned short* dst = attn + (size_t)(b*4096 + grow) * 1024 + h*64;
#pragma unroll
            for (int ni = 0; ni < 4; ++ni)
                dst[16*ni + l15] = f2bf(nacc[ni][r] * rd);
        }
        __builtin_amdgcn_sched_barrier(0);  // keep tile phases ordered
    }
}

// ------------------------------------------------------------ k_linear ----
// out[16384][1024] = attn_bf16 @ Wb^T + bias  (m97 structure, proven)
__global__ __launch_bounds__(256) void k_linear(const unsigned short* __restrict__ A,
                                                const unsigned short* __restrict__ Wb,
                                                const float* __restrict__ bias,
                                                float* __restrict__ out) {
    const int bm = blockIdx.x >> 3, bn = blockIdx.x & 7;
    const int tid = threadIdx.x;
    const int w = tid >> 6, lane = tid & 63, l15 = lane & 15, hh = lane >> 4;
    const int wm = w >> 1, wn = w & 1;
    const int m0 = bm * 128, n0 = bn * 128;

    __shared__ __align__(16) unsigned short As[128 * 64];
    __shared__ __align__(16) unsigned short Bs[128 * 64];

    const int srow = lane >> 3;
    const int scol = (lane & 7) * 8;

    f32x4 acc[4][4];
#pragma unroll
    for (int i = 0; i < 4; ++i)
#pragma unroll
        for (int j = 0; j < 4; ++j) acc[i][j] = (f32x4){0.f, 0.f, 0.f, 0.f};

    for (int kt = 0; kt < 16; ++kt) {
        __syncthreads();
#pragma unroll
        for (int i = 0; i < 4; ++i) {
            const int rr = (w*4 + i)*8 + srow;
            gload16(A  + (size_t)(m0 + rr) * 1024 + kt*64 + scol, &As[(w*4 + i) * 512]);
            gload16(Wb + (size_t)(n0 + rr) * 1024 + kt*64 + scol, &Bs[(w*4 + i) * 512]);
        }
        __syncthreads();
#pragma unroll
        for (int ks = 0; ks < 2; ++ks) {
            bf16x8 af[4], bw[4];
#pragma unroll
            for (int mi = 0; mi < 4; ++mi)
                af[mi] = *(const bf16x8*)&As[(wm*64 + 16*mi + l15) * 64 + ks*32 + 8*hh];
#pragma unroll
            for (int ni = 0; ni < 4; ++ni)
                bw[ni] = *(const bf16x8*)&Bs[(wn*64 + 16*ni + l15) * 64 + ks*32 + 8*hh];
#pragma unroll
            for (int mi = 0; mi < 4; ++mi)
#pragma unroll
                for (int ni = 0; ni < 4; ++ni)
                    acc[mi][ni] = mfma16(af[mi], bw[ni], acc[mi][ni]);
        }
    }

    float bs[4];
#pragma unroll
    for (int ni = 0; ni < 4; ++ni) bs[ni] = bias[n0 + wn*64 + 16*ni + l15];
#pragma unroll
    for (int mi = 0; mi < 4; ++mi) {
        const int row = m0 + wm*64 + 16*mi + 4*hh;
#pragma unroll
        for (int r = 0; r < 4; ++r) {
            float* o = out + (size_t)(row + r) * 1024 + n0 + wn*64;
#pragma unroll
            for (int ni = 0; ni < 4; ++ni)
                o[16*ni + l15] = acc[mi][ni][r] + bs[ni];
        }
    }
}

// ------------------------------------------------------------ launch ------
extern "C" void kernel_launch(void* const* d_in, const int* in_sizes, int n_in,
                              void* d_out, int out_size, void* d_ws, size_t ws_size,
                              hipStream_t stream) {
    const float* q    = (const float*)d_in[0];
    const float* k    = (const float*)d_in[1];
    const float* v    = (const float*)d_in[2];
    const float* W    = (const float*)d_in[3];
    const float* bias = (const float*)d_in[4];
    const float* proj = (const float*)d_in[5];
    float* out = (float*)d_out;

    int nchunk = 8;
    while (nchunk > 4) {
        size_t need = 33554432ull + 2097152 + 2097152 + 65536 + 32768 + 32768
                    + (size_t)nchunk * 65536
                    + (size_t)nchunk * 4194304
                    + 4096;
        if (need <= ws_size) break;
        nchunk >>= 1;
    }
    const int cshift = (nchunk == 8) ? 3 : 2;
    const int ntiles = 64 / nchunk;

    char* ws = (char*)d_ws;
    size_t off = 0;
    unsigned short* attn  = (unsigned short*)(ws + off); off += 33554432;
    unsigned short* ctxT  = (unsigned short*)(ws + off); off += 2097152;
    unsigned short* Wb    = (unsigned short*)(ws + off); off += 2097152;
    float*          ksum  = (float*)(ws + off);          off += 65536;
    unsigned short* projs = (unsigned short*)(ws + off); off += 32768;
    unsigned short* projz = (unsigned short*)(ws + off); off += 32768;
    float*          ksump = (float*)(ws + off);          off += (size_t)nchunk * 65536;
    float*          ctxp  = (float*)(ws + off);          off += (size_t)nchunk * 4194304;

    k_prep<<<dim3(4096), dim3(256), 0, stream>>>(W, proj, Wb, projs, projz);
    k_ctx<<<dim3(64 * nchunk), dim3(256), 0, stream>>>(k, v, projz, ctxp, ksump,
                                                       cshift, ntiles);
    k_reduce<<<dim3(256), dim3(256), 0, stream>>>(ctxp, ksump, ctxT, ksum, nchunk);
    k_qout<<<dim3(1024), dim3(256), 0, stream>>>(q, projz, ctxT, ksum, attn);
    k_linear<<<dim3(1024), dim3(256), 0, stream>>>(attn, Wb, bias, out);
}